// Round 18
// baseline (103.251 us; speedup 1.0000x reference)
//
#include <hip/hip_runtime.h>

#define NB 8
#define SEQ 4096
#define DIM 128
#define KVB 64
#define NTILES (SEQ / KVB)   // 64
#define HALF 32              // tiles per KV half
#define IMG_BYTES 32768
#define IMG_TOTAL ((size_t)NB * NTILES * IMG_BYTES)          // 16.78 MB
#define PART_ELEMS ((size_t)NB * SEQ * DIM)                  // 4.19M f32
#define PART_BYTES (PART_ELEMS * 4)                          // 16.78 MB
#define LS_ELEMS ((size_t)NB * SEQ)
#define WS_SPLIT (IMG_TOTAL + 2 * PART_BYTES + 2 * LS_ELEMS * 4)
#define WS_BASIC IMG_TOTAL
#define L2E 1.44269504088896f

typedef _Float16 f16x8 __attribute__((ext_vector_type(8)));
typedef __bf16 bf16x8 __attribute__((ext_vector_type(8)));
typedef float f32x4 __attribute__((ext_vector_type(4)));
typedef float f32x16 __attribute__((ext_vector_type(16)));

struct U4 { unsigned x, y, z, w; };

static __device__ __forceinline__ unsigned cvtpk_bf16(float a, float b) {
  unsigned d;
  asm("v_cvt_pk_bf16_f32 %0, %1, %2" : "=v"(d) : "v"(a), "v"(b));
  return d;
}

#define EXP2(x) __builtin_amdgcn_exp2f(x)  // range-certified |s|<~101

// ============================================================
// Pass 1 (verified r12/r17): K (f16) + V (bf16) 32KB tile images,
// 4-bit-row XOR swizzle, kappa map matching 32x32x16 C-layout.
// ============================================================
__global__ void prep_kv(const float* __restrict__ K, const float* __restrict__ V,
                        unsigned char* __restrict__ ws) {
  const int t = blockIdx.x;
  const int b = blockIdx.y;
  unsigned char* img = ws + ((size_t)b * NTILES + t) * IMG_BYTES;
  int4* kimg = (int4*)img;
  int4* vimg = (int4*)(img + 16384);
  const float* Kb = K + ((size_t)b * SEQ + t * KVB) * DIM;
  const float* Vb = V + ((size_t)b * SEQ + t * KVB) * DIM;
  const int tid = threadIdx.x;

#pragma unroll
  for (int p = 0; p < 4; ++p) {
    const int un = tid + 256 * p;
    const int kv = un >> 4;
    const int u = (un & 15) ^ (kv & 15);
    const int s = u >> 1, hh = u & 1;
    const float* src = Kb + (size_t)kv * DIM + 16 * s + 8 * hh;
    f16x8 hv;
#pragma unroll
    for (int j = 0; j < 8; ++j) hv[j] = (_Float16)src[j];
    kimg[un] = __builtin_bit_cast(int4, hv);
  }

#pragma unroll
  for (int p = 0; p < 4; ++p) {
    const int un = tid + 256 * p;
    const int rr = un >> 4;
    const int c = (un & 15) ^ (rr & 15);
    const int dhi = c >> 3, slot = c & 7;
    const int s2 = slot >> 1, hh = slot & 1;
    const int d = 64 * dhi + rr;
    bf16x8 hv;
#pragma unroll
    for (int e = 0; e < 8; ++e) {
      const int kv = 16 * s2 + 4 * hh + (e & 3) + 8 * (e >> 2);
      hv[e] = (__bf16)Vb[(size_t)kv * DIM + d];
    }
    vimg[un] = __builtin_bit_cast(int4, hv);
  }
}

// ============================================================
// Pass 2a: split-KV flash attention. 256 thr = 4 waves, each wave
// owns 64 q-rows (2 q-blocks) -> K/V LDS reads amortized 2x (LDS
// floor 13.7us/CU, MFMA 27us is top pipe). 1 wave/SIMD, ~400 live
// regs (512 budget). Block handles one KV half (32 tiles); writes
// UNNORMALIZED O + ls to ws (max-free softmax -> merge is a sum).
// ============================================================
__global__ __launch_bounds__(256, 1)
void attn_split(const float* __restrict__ Q, const unsigned char* __restrict__ ws,
                float* __restrict__ part, float* __restrict__ lsw) {
  __shared__ __align__(16) unsigned char smem[65536];  // 2 x 32KB

  const int tid = threadIdx.x;
  const int w4 = tid >> 6;
  const int l = tid & 63;
  const int l31 = l & 31;
  const int h = l >> 5;

  const int bid = blockIdx.x;          // ((qt*2 + kvh) << 3) | b
  const int b = bid & 7;               // batch -> XCD pinning
  const int kvh = (bid >> 3) & 1;      // KV half
  const int qt = bid >> 4;             // 0..15 (256 q-rows each)
  const size_t base = (size_t)b * SEQ * DIM;
  const int qrow0 = qt * 256 + w4 * 64 + l31;   // qb0 row; qb1 = +32

  // ---- Q fragments (x log2e) for both q-blocks
  f16x8 qfA[8], qfB[8];
#pragma unroll
  for (int qb = 0; qb < 2; ++qb) {
    const float* qp = Q + base + (size_t)(qrow0 + 32 * qb) * DIM + 8 * h;
#pragma unroll
    for (int s = 0; s < 8; ++s) {
      f32x4 a = *(const f32x4*)(qp + 16 * s);
      f32x4 c = *(const f32x4*)(qp + 16 * s + 4);
      f16x8 hv;
#pragma unroll
      for (int j = 0; j < 4; ++j) {
        hv[j] = (_Float16)(a[j] * L2E);
        hv[j + 4] = (_Float16)(c[j] * L2E);
      }
      if (qb == 0) qfA[s] = hv; else qfB[s] = hv;
    }
  }

  f32x16 oA[4], oB[4];
#pragma unroll
  for (int j = 0; j < 4; ++j) {
#pragma unroll
    for (int r = 0; r < 16; ++r) { oA[j][r] = 0.f; oB[j][r] = 0.f; }
  }
  float lsA = 0.f, lsB = 0.f;

  const unsigned char* wsb = ws + (size_t)b * NTILES * IMG_BYTES;

  auto STAGE = [&](int t, int bufsel) {  // 32KB image, 8KB per wave
    const unsigned char* src = wsb + (size_t)t * IMG_BYTES + w4 * 8192 + l * 16;
    unsigned char* dst = smem + bufsel * 32768 + w4 * 8192;
#pragma unroll
    for (int i = 0; i < 8; ++i) {
      __builtin_amdgcn_global_load_lds(
          (const __attribute__((address_space(1))) unsigned int*)(src + i * 1024),
          (__attribute__((address_space(3))) unsigned int*)(dst + i * 1024),
          16, 0, 0);
    }
  };

  // per-lane LDS bases, 4-bit swizzle folded (verified r12/r17)
  const int kb2 = (l31 * 256 + ((l31 & 15) * 16)) ^ (h * 16);
  int vb[4];
#pragma unroll
  for (int j = 0; j < 4; ++j) {
    const int rr = 32 * (j & 1) + l31;
    vb[j] = 16384 + rr * 256 + ((((j >> 1) * 8 + h) ^ (rr & 15)) * 16);
  }

  const int t0 = kvh * HALF;
  STAGE(t0, 0);
  __syncthreads();

#pragma unroll 1
  for (int i = 0; i < HALF; ++i) {
    const int cur = i & 1;
    if (i + 1 < HALF) STAGE(t0 + i + 1, cur ^ 1);
    const unsigned char* bufp = smem + cur * 32768;

    // ---- K fragments -> registers (read ONCE, used by both q-blocks)
    f16x8 kk0[8], kk1[8];
#pragma unroll
    for (int s = 0; s < 8; ++s) {
      kk0[s] = *(const f16x8*)(bufp + (kb2 ^ (32 * s)));
      kk1[s] = *(const f16x8*)(bufp + (kb2 ^ (32 * s)) + 8192);
    }

    // ---- QK^T: 4 independent chains (2 q-blocks x 2 kv-halves)
    f32x16 s0, s1, r0, r1;
#pragma unroll
    for (int r = 0; r < 16; ++r) { s0[r] = 0.f; s1[r] = 0.f; r0[r] = 0.f; r1[r] = 0.f; }
    __builtin_amdgcn_s_setprio(1);
#pragma unroll
    for (int s = 0; s < 8; ++s) {
      s0 = __builtin_amdgcn_mfma_f32_32x32x16_f16(kk0[s], qfA[s], s0, 0, 0, 0);
      s1 = __builtin_amdgcn_mfma_f32_32x32x16_f16(kk1[s], qfA[s], s1, 0, 0, 0);
    }
#pragma unroll
    for (int s = 0; s < 8; ++s) {
      r0 = __builtin_amdgcn_mfma_f32_32x32x16_f16(kk0[s], qfB[s], r0, 0, 0, 0);
      r1 = __builtin_amdgcn_mfma_f32_32x32x16_f16(kk1[s], qfB[s], r1, 0, 0, 0);
    }
    __builtin_amdgcn_s_setprio(0);

    // ---- V fragments -> registers (read ONCE, shared by both q-blocks)
    bf16x8 vf[16];
#pragma unroll
    for (int s2 = 0; s2 < 4; ++s2) {
#pragma unroll
      for (int j = 0; j < 4; ++j)
        vf[4 * s2 + j] = *(const bf16x8*)(bufp + (vb[j] ^ (32 * s2)));
    }

    // ---- softmax qb0 (VALU; overlaps qb1 QK^T tail + V loads)
    float a0 = 0.f, a1 = 0.f, a2 = 0.f, a3 = 0.f;
#pragma unroll
    for (int r = 0; r < 16; r += 4) {
      s0[r + 0] = EXP2(s0[r + 0]); s0[r + 1] = EXP2(s0[r + 1]);
      s0[r + 2] = EXP2(s0[r + 2]); s0[r + 3] = EXP2(s0[r + 3]);
      a0 += s0[r + 0]; a1 += s0[r + 1]; a2 += s0[r + 2]; a3 += s0[r + 3];
    }
#pragma unroll
    for (int r = 0; r < 16; r += 4) {
      s1[r + 0] = EXP2(s1[r + 0]); s1[r + 1] = EXP2(s1[r + 1]);
      s1[r + 2] = EXP2(s1[r + 2]); s1[r + 3] = EXP2(s1[r + 3]);
      a0 += s1[r + 0]; a1 += s1[r + 1]; a2 += s1[r + 2]; a3 += s1[r + 3];
    }
    lsA += (a0 + a1) + (a2 + a3);
    bf16x8 pbA[4];
#pragma unroll
    for (int u = 0; u < 2; ++u) {
      U4 ta = {cvtpk_bf16(s0[8 * u + 0], s0[8 * u + 1]),
               cvtpk_bf16(s0[8 * u + 2], s0[8 * u + 3]),
               cvtpk_bf16(s0[8 * u + 4], s0[8 * u + 5]),
               cvtpk_bf16(s0[8 * u + 6], s0[8 * u + 7])};
      U4 tb = {cvtpk_bf16(s1[8 * u + 0], s1[8 * u + 1]),
               cvtpk_bf16(s1[8 * u + 2], s1[8 * u + 3]),
               cvtpk_bf16(s1[8 * u + 4], s1[8 * u + 5]),
               cvtpk_bf16(s1[8 * u + 6], s1[8 * u + 7])};
      pbA[u] = __builtin_bit_cast(bf16x8, ta);
      pbA[2 + u] = __builtin_bit_cast(bf16x8, tb);
    }

    // ---- PV qb0
    __builtin_amdgcn_s_setprio(1);
#pragma unroll
    for (int s2 = 0; s2 < 4; ++s2) {
#pragma unroll
      for (int j = 0; j < 4; ++j)
        oA[j] = __builtin_amdgcn_mfma_f32_32x32x16_bf16(vf[4 * s2 + j], pbA[s2],
                                                        oA[j], 0, 0, 0);
    }
    __builtin_amdgcn_s_setprio(0);

    // ---- softmax qb1 (overlaps PV qb0 MFMAs)
    float b0 = 0.f, b1 = 0.f, b2 = 0.f, b3 = 0.f;
#pragma unroll
    for (int r = 0; r < 16; r += 4) {
      r0[r + 0] = EXP2(r0[r + 0]); r0[r + 1] = EXP2(r0[r + 1]);
      r0[r + 2] = EXP2(r0[r + 2]); r0[r + 3] = EXP2(r0[r + 3]);
      b0 += r0[r + 0]; b1 += r0[r + 1]; b2 += r0[r + 2]; b3 += r0[r + 3];
    }
#pragma unroll
    for (int r = 0; r < 16; r += 4) {
      r1[r + 0] = EXP2(r1[r + 0]); r1[r + 1] = EXP2(r1[r + 1]);
      r1[r + 2] = EXP2(r1[r + 2]); r1[r + 3] = EXP2(r1[r + 3]);
      b0 += r1[r + 0]; b1 += r1[r + 1]; b2 += r1[r + 2]; b3 += r1[r + 3];
    }
    lsB += (b0 + b1) + (b2 + b3);
    bf16x8 pbB[4];
#pragma unroll
    for (int u = 0; u < 2; ++u) {
      U4 ta = {cvtpk_bf16(r0[8 * u + 0], r0[8 * u + 1]),
               cvtpk_bf16(r0[8 * u + 2], r0[8 * u + 3]),
               cvtpk_bf16(r0[8 * u + 4], r0[8 * u + 5]),
               cvtpk_bf16(r0[8 * u + 6], r0[8 * u + 7])};
      U4 tb = {cvtpk_bf16(r1[8 * u + 0], r1[8 * u + 1]),
               cvtpk_bf16(r1[8 * u + 2], r1[8 * u + 3]),
               cvtpk_bf16(r1[8 * u + 4], r1[8 * u + 5]),
               cvtpk_bf16(r1[8 * u + 6], r1[8 * u + 7])};
      pbB[u] = __builtin_bit_cast(bf16x8, ta);
      pbB[2 + u] = __builtin_bit_cast(bf16x8, tb);
    }

    // ---- PV qb1
    __builtin_amdgcn_s_setprio(1);
#pragma unroll
    for (int s2 = 0; s2 < 4; ++s2) {
#pragma unroll
      for (int j = 0; j < 4; ++j)
        oB[j] = __builtin_amdgcn_mfma_f32_32x32x16_bf16(vf[4 * s2 + j], pbB[s2],
                                                        oB[j], 0, 0, 0);
    }
    __builtin_amdgcn_s_setprio(0);
    __syncthreads();
  }

  // ---- partial epilogue: UNNORMALIZED store + ls
  lsA += __shfl_xor(lsA, 32);
  lsB += __shfl_xor(lsB, 32);
  float* P = part + (size_t)kvh * PART_ELEMS + base;
#pragma unroll
  for (int qb = 0; qb < 2; ++qb) {
    float* Pb = P + (size_t)(qrow0 + 32 * qb) * DIM;
#pragma unroll
    for (int j = 0; j < 4; ++j) {
#pragma unroll
      for (int rq = 0; rq < 4; ++rq) {
        f32x4 res;
#pragma unroll
        for (int r = 0; r < 4; ++r)
          res[r] = qb == 0 ? oA[j][4 * rq + r] : oB[j][4 * rq + r];
        *(f32x4*)(Pb + 32 * j + 8 * rq + 4 * h) = res;
      }
    }
  }
  if (h == 0) {
    lsw[(size_t)kvh * LS_ELEMS + b * SEQ + qrow0] = lsA;
    lsw[(size_t)kvh * LS_ELEMS + b * SEQ + qrow0 + 32] = lsB;
  }
}

// ============================================================
// Pass 2b: combine halves: out = (p0+p1)/(l0+l1)
// ============================================================
__global__ void combine(const float* __restrict__ part,
                        const float* __restrict__ lsw,
                        float* __restrict__ out) {
  const size_t idx = (size_t)blockIdx.x * 256 + threadIdx.x;  // quad index
  const f32x4 a = ((const f32x4*)part)[idx];
  const f32x4 b = ((const f32x4*)(part + PART_ELEMS))[idx];
  const size_t row = idx >> 5;  // 32 quads per 128-elem row
  const float inv = 1.0f / (lsw[row] + lsw[LS_ELEMS + row]);
  f32x4 r;
#pragma unroll
  for (int j = 0; j < 4; ++j) r[j] = (a[j] + b[j]) * inv;
  ((f32x4*)out)[idx] = r;
}

// ============================================================
// Fallback (r17 kernel, verified): used when ws < WS_SPLIT.
// ============================================================
__global__ __launch_bounds__(256, 2)
void attn_fwd15(const float* __restrict__ Q, const unsigned char* __restrict__ ws,
                float* __restrict__ O) {
  __shared__ __align__(16) unsigned char smem[65536];

  const int tid = threadIdx.x;
  const int w4 = tid >> 6;
  const int l = tid & 63;
  const int l31 = l & 31;
  const int h = l >> 5;

  const int bid = blockIdx.x;
  const int b = bid & 7;
  const int qt = bid >> 3;
  const size_t base = (size_t)b * SEQ * DIM;
  const int qrow = qt * 128 + w4 * 32 + l31;

  f16x8 qf[8];
  {
    const float* qp = Q + base + (size_t)qrow * DIM + 8 * h;
#pragma unroll
    for (int s = 0; s < 8; ++s) {
      f32x4 a = *(const f32x4*)(qp + 16 * s);
      f32x4 c = *(const f32x4*)(qp + 16 * s + 4);
      f16x8 hv;
#pragma unroll
      for (int j = 0; j < 4; ++j) {
        hv[j] = (_Float16)(a[j] * L2E);
        hv[j + 4] = (_Float16)(c[j] * L2E);
      }
      qf[s] = hv;
    }
  }

  f32x16 o[4];
#pragma unroll
  for (int j = 0; j < 4; ++j) {
#pragma unroll
    for (int r = 0; r < 16; ++r) o[j][r] = 0.f;
  }
  float ls = 0.f;

  const unsigned char* wsb = ws + (size_t)b * NTILES * IMG_BYTES;

  auto STAGE = [&](int t, int bufsel) {
    const unsigned char* src = wsb + (size_t)t * IMG_BYTES + w4 * 8192 + l * 16;
    unsigned char* dst = smem + bufsel * 32768 + w4 * 8192;
#pragma unroll
    for (int i = 0; i < 8; ++i) {
      __builtin_amdgcn_global_load_lds(
          (const __attribute__((address_space(1))) unsigned int*)(src + i * 1024),
          (__attribute__((address_space(3))) unsigned int*)(dst + i * 1024),
          16, 0, 0);
    }
  };

  const int kb2 = (l31 * 256 + ((l31 & 15) * 16)) ^ (h * 16);
  int vb[4];
#pragma unroll
  for (int j = 0; j < 4; ++j) {
    const int rr = 32 * (j & 1) + l31;
    vb[j] = 16384 + rr * 256 + ((((j >> 1) * 8 + h) ^ (rr & 15)) * 16);
  }

  STAGE(0, 0);
  __syncthreads();

  for (int t = 0; t < NTILES; ++t) {
    const int cur = t & 1;
    if (t + 1 < NTILES) STAGE(t + 1, cur ^ 1);
    const unsigned char* bufp = smem + cur * 32768;

    f32x16 s0, s1;
#pragma unroll
    for (int r = 0; r < 16; ++r) { s0[r] = 0.f; s1[r] = 0.f; }
    __builtin_amdgcn_s_setprio(1);
#pragma unroll
    for (int s = 0; s < 8; ++s) {
      f16x8 k0 = *(const f16x8*)(bufp + (kb2 ^ (32 * s)));
      s0 = __builtin_amdgcn_mfma_f32_32x32x16_f16(k0, qf[s], s0, 0, 0, 0);
    }
#pragma unroll
    for (int s = 0; s < 8; ++s) {
      f16x8 k1 = *(const f16x8*)(bufp + (kb2 ^ (32 * s)) + 8192);
      s1 = __builtin_amdgcn_mfma_f32_32x32x16_f16(k1, qf[s], s1, 0, 0, 0);
    }
    __builtin_amdgcn_s_setprio(0);

    float a0 = 0.f, a1 = 0.f, a2 = 0.f, a3 = 0.f;
#pragma unroll
    for (int r = 0; r < 16; r += 4) {
      s0[r + 0] = EXP2(s0[r + 0]); s0[r + 1] = EXP2(s0[r + 1]);
      s0[r + 2] = EXP2(s0[r + 2]); s0[r + 3] = EXP2(s0[r + 3]);
      a0 += s0[r + 0]; a1 += s0[r + 1]; a2 += s0[r + 2]; a3 += s0[r + 3];
    }
    bf16x8 pb0[2];
#pragma unroll
    for (int u = 0; u < 2; ++u) {
      U4 t0 = {cvtpk_bf16(s0[8 * u + 0], s0[8 * u + 1]),
               cvtpk_bf16(s0[8 * u + 2], s0[8 * u + 3]),
               cvtpk_bf16(s0[8 * u + 4], s0[8 * u + 5]),
               cvtpk_bf16(s0[8 * u + 6], s0[8 * u + 7])};
      pb0[u] = __builtin_bit_cast(bf16x8, t0);
    }

    __builtin_amdgcn_s_setprio(1);
#pragma unroll
    for (int s2 = 0; s2 < 2; ++s2) {
#pragma unroll
      for (int j = 0; j < 4; ++j) {
        bf16x8 vf = *(const bf16x8*)(bufp + (vb[j] ^ (32 * s2)));
        o[j] = __builtin_amdgcn_mfma_f32_32x32x16_bf16(vf, pb0[s2], o[j], 0, 0, 0);
      }
    }
    __builtin_amdgcn_s_setprio(0);

#pragma unroll
    for (int r = 0; r < 16; r += 4) {
      s1[r + 0] = EXP2(s1[r + 0]); s1[r + 1] = EXP2(s1[r + 1]);
      s1[r + 2] = EXP2(s1[r + 2]); s1[r + 3] = EXP2(s1[r + 3]);
      a0 += s1[r + 0]; a1 += s1[r + 1]; a2 += s1[r + 2]; a3 += s1[r + 3];
    }
    ls += (a0 + a1) + (a2 + a3);
    bf16x8 pb1[2];
#pragma unroll
    for (int u = 0; u < 2; ++u) {
      U4 t1 = {cvtpk_bf16(s1[8 * u + 0], s1[8 * u + 1]),
               cvtpk_bf16(s1[8 * u + 2], s1[8 * u + 3]),
               cvtpk_bf16(s1[8 * u + 4], s1[8 * u + 5]),
               cvtpk_bf16(s1[8 * u + 6], s1[8 * u + 7])};
      pb1[u] = __builtin_bit_cast(bf16x8, t1);
    }

    __builtin_amdgcn_s_setprio(1);
#pragma unroll
    for (int s2 = 2; s2 < 4; ++s2) {
#pragma unroll
      for (int j = 0; j < 4; ++j) {
        bf16x8 vf = *(const bf16x8*)(bufp + (vb[j] ^ (32 * s2)));
        o[j] = __builtin_amdgcn_mfma_f32_32x32x16_bf16(vf, pb1[s2 - 2], o[j], 0, 0, 0);
      }
    }
    __builtin_amdgcn_s_setprio(0);
    __syncthreads();
  }

  ls += __shfl_xor(ls, 32);
  const float inv = 1.0f / ls;
  float* Ob = O + base + (size_t)qrow * DIM;
#pragma unroll
  for (int j = 0; j < 4; ++j) {
#pragma unroll
    for (int rq = 0; rq < 4; ++rq) {
      f32x4 res;
#pragma unroll
      for (int r = 0; r < 4; ++r) res[r] = o[j][4 * rq + r] * inv;
      *(f32x4*)(Ob + 32 * j + 8 * rq + 4 * h) = res;
    }
  }
}

extern "C" void kernel_launch(void* const* d_in, const int* in_sizes, int n_in,
                              void* d_out, int out_size, void* d_ws,
                              size_t ws_size, hipStream_t stream) {
  const float* Q = (const float*)d_in[0];
  const float* K = (const float*)d_in[1];
  const float* V = (const float*)d_in[2];
  float* Out = (float*)d_out;
  unsigned char* ws = (unsigned char*)d_ws;
  if (ws_size < WS_BASIC) return;
  prep_kv<<<dim3(NTILES, NB), dim3(256), 0, stream>>>(K, V, ws);
  if (ws_size >= WS_SPLIT) {
    float* part = (float*)(ws + IMG_TOTAL);
    float* lsw = (float*)(ws + IMG_TOTAL + 2 * PART_BYTES);
    attn_split<<<dim3(256), dim3(256), 0, stream>>>(Q, ws, part, lsw);
    combine<<<dim3(PART_ELEMS / 4 / 256), dim3(256), 0, stream>>>(part, lsw, Out);
  } else {
    attn_fwd15<<<dim3(SEQ / 128 * NB), dim3(256), 0, stream>>>(Q, ws, Out);
  }
}

// Round 19
// 101.850 us; speedup vs baseline: 1.0138x; 1.0138x over previous
//
#include <hip/hip_runtime.h>

#define NB 8
#define SEQ 4096
#define DIM 128
#define KVB 64
#define NTILES (SEQ / KVB)   // 64
#define HALF 32              // tiles per KV half
#define IMG_BYTES 32768
#define IMG_TOTAL ((size_t)NB * NTILES * IMG_BYTES)          // 16.78 MB
#define PART_ELEMS ((size_t)NB * SEQ * DIM)                  // 4.19M f32
#define PART_BYTES (PART_ELEMS * 4)                          // 16.78 MB
#define LS_ELEMS ((size_t)NB * SEQ)
#define WS_SPLIT (IMG_TOTAL + 2 * PART_BYTES + 2 * LS_ELEMS * 4)
#define WS_BASIC IMG_TOTAL
#define L2E 1.44269504088896f

typedef _Float16 f16x8 __attribute__((ext_vector_type(8)));
typedef __bf16 bf16x8 __attribute__((ext_vector_type(8)));
typedef float f32x4 __attribute__((ext_vector_type(4)));
typedef float f32x16 __attribute__((ext_vector_type(16)));

struct U4 { unsigned x, y, z, w; };

static __device__ __forceinline__ unsigned cvtpk_bf16(float a, float b) {
  unsigned d;
  asm("v_cvt_pk_bf16_f32 %0, %1, %2" : "=v"(d) : "v"(a), "v"(b));
  return d;
}

#define EXP2(x) __builtin_amdgcn_exp2f(x)  // range-certified |s|<~101

// ============================================================
// Pass 1 (verified r12-r18): K (f16) + V (bf16) 32KB tile images,
// 4-bit-row XOR swizzle, kappa map matching 32x32x16 C-layout.
// ============================================================
__global__ void prep_kv(const float* __restrict__ K, const float* __restrict__ V,
                        unsigned char* __restrict__ ws) {
  const int t = blockIdx.x;
  const int b = blockIdx.y;
  unsigned char* img = ws + ((size_t)b * NTILES + t) * IMG_BYTES;
  int4* kimg = (int4*)img;
  int4* vimg = (int4*)(img + 16384);
  const float* Kb = K + ((size_t)b * SEQ + t * KVB) * DIM;
  const float* Vb = V + ((size_t)b * SEQ + t * KVB) * DIM;
  const int tid = threadIdx.x;

#pragma unroll
  for (int p = 0; p < 4; ++p) {
    const int un = tid + 256 * p;
    const int kv = un >> 4;
    const int u = (un & 15) ^ (kv & 15);
    const int s = u >> 1, hh = u & 1;
    const float* src = Kb + (size_t)kv * DIM + 16 * s + 8 * hh;
    f16x8 hv;
#pragma unroll
    for (int j = 0; j < 8; ++j) hv[j] = (_Float16)src[j];
    kimg[un] = __builtin_bit_cast(int4, hv);
  }

#pragma unroll
  for (int p = 0; p < 4; ++p) {
    const int un = tid + 256 * p;
    const int rr = un >> 4;
    const int c = (un & 15) ^ (rr & 15);
    const int dhi = c >> 3, slot = c & 7;
    const int s2 = slot >> 1, hh = slot & 1;
    const int d = 64 * dhi + rr;
    bf16x8 hv;
#pragma unroll
    for (int e = 0; e < 8; ++e) {
      const int kv = 16 * s2 + 4 * hh + (e & 3) + 8 * (e >> 2);
      hv[e] = (__bf16)Vb[(size_t)kv * DIM + d];
    }
    vimg[un] = __builtin_bit_cast(int4, hv);
  }
}

// ============================================================
// Pass 2a: split-KV flash attention, r17 inner loop (verified):
// 256 thr = 4 waves x 32 q-rows, 64KB LDS -> with grid 512
// (32 qt x 2 kvh x 8 b) TWO INDEPENDENT blocks co-reside per CU:
// each SIMD hosts 2 waves from DIFFERENT blocks (not barrier-locked
// together) -> cross-phase MFMA/VALU/LDS overlap at zero register
// cost (96 VGPR + 64 AGPR = 160 <= 256). Co-resident pair (qt,
// qt+16) shares kvh+batch -> identical KV reads, L2 dedup.
// Writes UNNORMALIZED O + ls (max-free softmax -> merge is a sum).
// ============================================================
__global__ __launch_bounds__(256, 2)
void attn_split(const float* __restrict__ Q, const unsigned char* __restrict__ ws,
                float* __restrict__ part, float* __restrict__ lsw) {
  __shared__ __align__(16) unsigned char smem[65536];  // 2 x 32KB

  const int tid = threadIdx.x;
  const int w4 = tid >> 6;
  const int l = tid & 63;
  const int l31 = l & 31;
  const int h = l >> 5;

  const int bid = blockIdx.x;          // ((qt*2 + kvh) << 3) | b
  const int b = bid & 7;               // batch -> XCD pinning
  const int kvh = (bid >> 3) & 1;      // KV half
  const int qt = bid >> 4;             // 0..31 (128 q-rows each)
  const size_t base = (size_t)b * SEQ * DIM;
  const int qrow = qt * 128 + w4 * 32 + l31;  // this lane's q row

  // ---- Q fragments (x log2e): qf[s][e] = Q[qrow][16s + 8h + e]
  f16x8 qf[8];
  {
    const float* qp = Q + base + (size_t)qrow * DIM + 8 * h;
#pragma unroll
    for (int s = 0; s < 8; ++s) {
      f32x4 a = *(const f32x4*)(qp + 16 * s);
      f32x4 c = *(const f32x4*)(qp + 16 * s + 4);
      f16x8 hv;
#pragma unroll
      for (int j = 0; j < 4; ++j) {
        hv[j] = (_Float16)(a[j] * L2E);
        hv[j + 4] = (_Float16)(c[j] * L2E);
      }
      qf[s] = hv;
    }
  }

  f32x16 o[4];
#pragma unroll
  for (int j = 0; j < 4; ++j) {
#pragma unroll
    for (int r = 0; r < 16; ++r) o[j][r] = 0.f;
  }
  float ls = 0.f;

  const unsigned char* wsb = ws + (size_t)b * NTILES * IMG_BYTES;

  auto STAGE = [&](int t, int bufsel) {  // 32KB image, 8KB per wave
    const unsigned char* src = wsb + (size_t)t * IMG_BYTES + w4 * 8192 + l * 16;
    unsigned char* dst = smem + bufsel * 32768 + w4 * 8192;
#pragma unroll
    for (int i = 0; i < 8; ++i) {
      __builtin_amdgcn_global_load_lds(
          (const __attribute__((address_space(1))) unsigned int*)(src + i * 1024),
          (__attribute__((address_space(3))) unsigned int*)(dst + i * 1024),
          16, 0, 0);
    }
  };

  // per-lane LDS byte bases, 4-bit swizzle folded (verified r12/r17)
  const int kb2 = (l31 * 256 + ((l31 & 15) * 16)) ^ (h * 16);
  int vb[4];
#pragma unroll
  for (int j = 0; j < 4; ++j) {
    const int rr = 32 * (j & 1) + l31;
    vb[j] = 16384 + rr * 256 + ((((j >> 1) * 8 + h) ^ (rr & 15)) * 16);
  }

  const int t0 = kvh * HALF;
  STAGE(t0, 0);
  __syncthreads();

#pragma unroll 1
  for (int i = 0; i < HALF; ++i) {
    const int cur = i & 1;
    if (i + 1 < HALF) STAGE(t0 + i + 1, cur ^ 1);
    const unsigned char* bufp = smem + cur * 32768;

    // ---- S = K Q^T : lane q = l31; kv = 32T + (r&3)+8(r>>2)+4h
    f32x16 s0, s1;
#pragma unroll
    for (int r = 0; r < 16; ++r) { s0[r] = 0.f; s1[r] = 0.f; }
    __builtin_amdgcn_s_setprio(1);
#pragma unroll
    for (int s = 0; s < 8; ++s) {
      f16x8 k0 = *(const f16x8*)(bufp + (kb2 ^ (32 * s)));
      s0 = __builtin_amdgcn_mfma_f32_32x32x16_f16(k0, qf[s], s0, 0, 0, 0);
    }
#pragma unroll
    for (int s = 0; s < 8; ++s) {
      f16x8 k1 = *(const f16x8*)(bufp + (kb2 ^ (32 * s)) + 8192);
      s1 = __builtin_amdgcn_mfma_f32_32x32x16_f16(k1, qf[s], s1, 0, 0, 0);
    }
    __builtin_amdgcn_s_setprio(0);

    // ---- softmax tile 0 (overlaps s1's MFMA tail)
    float a0 = 0.f, a1 = 0.f, a2 = 0.f, a3 = 0.f;
#pragma unroll
    for (int r = 0; r < 16; r += 4) {
      s0[r + 0] = EXP2(s0[r + 0]); s0[r + 1] = EXP2(s0[r + 1]);
      s0[r + 2] = EXP2(s0[r + 2]); s0[r + 3] = EXP2(s0[r + 3]);
      a0 += s0[r + 0]; a1 += s0[r + 1]; a2 += s0[r + 2]; a3 += s0[r + 3];
    }
    bf16x8 pb0[2];
#pragma unroll
    for (int u = 0; u < 2; ++u) {
      U4 t0v = {cvtpk_bf16(s0[8 * u + 0], s0[8 * u + 1]),
                cvtpk_bf16(s0[8 * u + 2], s0[8 * u + 3]),
                cvtpk_bf16(s0[8 * u + 4], s0[8 * u + 5]),
                cvtpk_bf16(s0[8 * u + 6], s0[8 * u + 7])};
      pb0[u] = __builtin_bit_cast(bf16x8, t0v);
    }

    // ---- PV half 1 (tile 0: s2 = 0,1)
    __builtin_amdgcn_s_setprio(1);
#pragma unroll
    for (int s2 = 0; s2 < 2; ++s2) {
#pragma unroll
      for (int j = 0; j < 4; ++j) {
        bf16x8 vf = *(const bf16x8*)(bufp + (vb[j] ^ (32 * s2)));
        o[j] = __builtin_amdgcn_mfma_f32_32x32x16_bf16(vf, pb0[s2], o[j], 0, 0, 0);
      }
    }
    __builtin_amdgcn_s_setprio(0);

    // ---- softmax tile 1 (overlaps PV-half-1 MFMAs)
#pragma unroll
    for (int r = 0; r < 16; r += 4) {
      s1[r + 0] = EXP2(s1[r + 0]); s1[r + 1] = EXP2(s1[r + 1]);
      s1[r + 2] = EXP2(s1[r + 2]); s1[r + 3] = EXP2(s1[r + 3]);
      a0 += s1[r + 0]; a1 += s1[r + 1]; a2 += s1[r + 2]; a3 += s1[r + 3];
    }
    ls += (a0 + a1) + (a2 + a3);
    bf16x8 pb1[2];
#pragma unroll
    for (int u = 0; u < 2; ++u) {
      U4 t1v = {cvtpk_bf16(s1[8 * u + 0], s1[8 * u + 1]),
                cvtpk_bf16(s1[8 * u + 2], s1[8 * u + 3]),
                cvtpk_bf16(s1[8 * u + 4], s1[8 * u + 5]),
                cvtpk_bf16(s1[8 * u + 6], s1[8 * u + 7])};
      pb1[u] = __builtin_bit_cast(bf16x8, t1v);
    }

    // ---- PV half 2 (tile 1: s2 = 2,3)
    __builtin_amdgcn_s_setprio(1);
#pragma unroll
    for (int s2 = 2; s2 < 4; ++s2) {
#pragma unroll
      for (int j = 0; j < 4; ++j) {
        bf16x8 vf = *(const bf16x8*)(bufp + (vb[j] ^ (32 * s2)));
        o[j] = __builtin_amdgcn_mfma_f32_32x32x16_bf16(vf, pb1[s2 - 2], o[j], 0, 0, 0);
      }
    }
    __builtin_amdgcn_s_setprio(0);
    __syncthreads();  // 4-wave barrier; the OTHER block on this CU runs free
  }

  // ---- partial epilogue: UNNORMALIZED store + ls
  ls += __shfl_xor(ls, 32);
  float* Pb = part + (size_t)kvh * PART_ELEMS + base + (size_t)qrow * DIM;
#pragma unroll
  for (int j = 0; j < 4; ++j) {
#pragma unroll
    for (int rq = 0; rq < 4; ++rq) {
      f32x4 res;
#pragma unroll
      for (int r = 0; r < 4; ++r) res[r] = o[j][4 * rq + r];
      *(f32x4*)(Pb + 32 * j + 8 * rq + 4 * h) = res;
    }
  }
  if (h == 0) lsw[(size_t)kvh * LS_ELEMS + b * SEQ + qrow] = ls;
}

// ============================================================
// Pass 2b: combine halves: out = (p0+p1)/(l0+l1)
// ============================================================
__global__ void combine(const float* __restrict__ part,
                        const float* __restrict__ lsw,
                        float* __restrict__ out) {
  const size_t idx = (size_t)blockIdx.x * 256 + threadIdx.x;  // quad index
  const f32x4 a = ((const f32x4*)part)[idx];
  const f32x4 b = ((const f32x4*)(part + PART_ELEMS))[idx];
  const size_t row = idx >> 5;  // 32 quads per 128-elem row
  const float inv = 1.0f / (lsw[row] + lsw[LS_ELEMS + row]);
  f32x4 r;
#pragma unroll
  for (int j = 0; j < 4; ++j) r[j] = (a[j] + b[j]) * inv;
  ((f32x4*)out)[idx] = r;
}

// ============================================================
// Fallback (r17 kernel, verified) when ws < WS_SPLIT.
// ============================================================
__global__ __launch_bounds__(256, 2)
void attn_fwd15(const float* __restrict__ Q, const unsigned char* __restrict__ ws,
                float* __restrict__ O) {
  __shared__ __align__(16) unsigned char smem[65536];

  const int tid = threadIdx.x;
  const int w4 = tid >> 6;
  const int l = tid & 63;
  const int l31 = l & 31;
  const int h = l >> 5;

  const int bid = blockIdx.x;
  const int b = bid & 7;
  const int qt = bid >> 3;
  const size_t base = (size_t)b * SEQ * DIM;
  const int qrow = qt * 128 + w4 * 32 + l31;

  f16x8 qf[8];
  {
    const float* qp = Q + base + (size_t)qrow * DIM + 8 * h;
#pragma unroll
    for (int s = 0; s < 8; ++s) {
      f32x4 a = *(const f32x4*)(qp + 16 * s);
      f32x4 c = *(const f32x4*)(qp + 16 * s + 4);
      f16x8 hv;
#pragma unroll
      for (int j = 0; j < 4; ++j) {
        hv[j] = (_Float16)(a[j] * L2E);
        hv[j + 4] = (_Float16)(c[j] * L2E);
      }
      qf[s] = hv;
    }
  }

  f32x16 o[4];
#pragma unroll
  for (int j = 0; j < 4; ++j) {
#pragma unroll
    for (int r = 0; r < 16; ++r) o[j][r] = 0.f;
  }
  float ls = 0.f;

  const unsigned char* wsb = ws + (size_t)b * NTILES * IMG_BYTES;

  auto STAGE = [&](int t, int bufsel) {
    const unsigned char* src = wsb + (size_t)t * IMG_BYTES + w4 * 8192 + l * 16;
    unsigned char* dst = smem + bufsel * 32768 + w4 * 8192;
#pragma unroll
    for (int i = 0; i < 8; ++i) {
      __builtin_amdgcn_global_load_lds(
          (const __attribute__((address_space(1))) unsigned int*)(src + i * 1024),
          (__attribute__((address_space(3))) unsigned int*)(dst + i * 1024),
          16, 0, 0);
    }
  };

  const int kb2 = (l31 * 256 + ((l31 & 15) * 16)) ^ (h * 16);
  int vb[4];
#pragma unroll
  for (int j = 0; j < 4; ++j) {
    const int rr = 32 * (j & 1) + l31;
    vb[j] = 16384 + rr * 256 + ((((j >> 1) * 8 + h) ^ (rr & 15)) * 16);
  }

  STAGE(0, 0);
  __syncthreads();

  for (int t = 0; t < NTILES; ++t) {
    const int cur = t & 1;
    if (t + 1 < NTILES) STAGE(t + 1, cur ^ 1);
    const unsigned char* bufp = smem + cur * 32768;

    f32x16 s0, s1;
#pragma unroll
    for (int r = 0; r < 16; ++r) { s0[r] = 0.f; s1[r] = 0.f; }
    __builtin_amdgcn_s_setprio(1);
#pragma unroll
    for (int s = 0; s < 8; ++s) {
      f16x8 k0 = *(const f16x8*)(bufp + (kb2 ^ (32 * s)));
      s0 = __builtin_amdgcn_mfma_f32_32x32x16_f16(k0, qf[s], s0, 0, 0, 0);
    }
#pragma unroll
    for (int s = 0; s < 8; ++s) {
      f16x8 k1 = *(const f16x8*)(bufp + (kb2 ^ (32 * s)) + 8192);
      s1 = __builtin_amdgcn_mfma_f32_32x32x16_f16(k1, qf[s], s1, 0, 0, 0);
    }
    __builtin_amdgcn_s_setprio(0);

    float a0 = 0.f, a1 = 0.f, a2 = 0.f, a3 = 0.f;
#pragma unroll
    for (int r = 0; r < 16; r += 4) {
      s0[r + 0] = EXP2(s0[r + 0]); s0[r + 1] = EXP2(s0[r + 1]);
      s0[r + 2] = EXP2(s0[r + 2]); s0[r + 3] = EXP2(s0[r + 3]);
      a0 += s0[r + 0]; a1 += s0[r + 1]; a2 += s0[r + 2]; a3 += s0[r + 3];
    }
    bf16x8 pb0[2];
#pragma unroll
    for (int u = 0; u < 2; ++u) {
      U4 t0 = {cvtpk_bf16(s0[8 * u + 0], s0[8 * u + 1]),
               cvtpk_bf16(s0[8 * u + 2], s0[8 * u + 3]),
               cvtpk_bf16(s0[8 * u + 4], s0[8 * u + 5]),
               cvtpk_bf16(s0[8 * u + 6], s0[8 * u + 7])};
      pb0[u] = __builtin_bit_cast(bf16x8, t0);
    }

    __builtin_amdgcn_s_setprio(1);
#pragma unroll
    for (int s2 = 0; s2 < 2; ++s2) {
#pragma unroll
      for (int j = 0; j < 4; ++j) {
        bf16x8 vf = *(const bf16x8*)(bufp + (vb[j] ^ (32 * s2)));
        o[j] = __builtin_amdgcn_mfma_f32_32x32x16_bf16(vf, pb0[s2], o[j], 0, 0, 0);
      }
    }
    __builtin_amdgcn_s_setprio(0);

#pragma unroll
    for (int r = 0; r < 16; r += 4) {
      s1[r + 0] = EXP2(s1[r + 0]); s1[r + 1] = EXP2(s1[r + 1]);
      s1[r + 2] = EXP2(s1[r + 2]); s1[r + 3] = EXP2(s1[r + 3]);
      a0 += s1[r + 0]; a1 += s1[r + 1]; a2 += s1[r + 2]; a3 += s1[r + 3];
    }
    ls += (a0 + a1) + (a2 + a3);
    bf16x8 pb1[2];
#pragma unroll
    for (int u = 0; u < 2; ++u) {
      U4 t1 = {cvtpk_bf16(s1[8 * u + 0], s1[8 * u + 1]),
               cvtpk_bf16(s1[8 * u + 2], s1[8 * u + 3]),
               cvtpk_bf16(s1[8 * u + 4], s1[8 * u + 5]),
               cvtpk_bf16(s1[8 * u + 6], s1[8 * u + 7])};
      pb1[u] = __builtin_bit_cast(bf16x8, t1);
    }

    __builtin_amdgcn_s_setprio(1);
#pragma unroll
    for (int s2 = 2; s2 < 4; ++s2) {
#pragma unroll
      for (int j = 0; j < 4; ++j) {
        bf16x8 vf = *(const bf16x8*)(bufp + (vb[j] ^ (32 * s2)));
        o[j] = __builtin_amdgcn_mfma_f32_32x32x16_bf16(vf, pb1[s2 - 2], o[j], 0, 0, 0);
      }
    }
    __builtin_amdgcn_s_setprio(0);
    __syncthreads();
  }

  ls += __shfl_xor(ls, 32);
  const float inv = 1.0f / ls;
  float* Ob = O + base + (size_t)qrow * DIM;
#pragma unroll
  for (int j = 0; j < 4; ++j) {
#pragma unroll
    for (int rq = 0; rq < 4; ++rq) {
      f32x4 res;
#pragma unroll
      for (int r = 0; r < 4; ++r) res[r] = o[j][4 * rq + r] * inv;
      *(f32x4*)(Ob + 32 * j + 8 * rq + 4 * h) = res;
    }
  }
}

extern "C" void kernel_launch(void* const* d_in, const int* in_sizes, int n_in,
                              void* d_out, int out_size, void* d_ws,
                              size_t ws_size, hipStream_t stream) {
  const float* Q = (const float*)d_in[0];
  const float* K = (const float*)d_in[1];
  const float* V = (const float*)d_in[2];
  float* Out = (float*)d_out;
  unsigned char* ws = (unsigned char*)d_ws;
  if (ws_size < WS_BASIC) return;
  prep_kv<<<dim3(NTILES, NB), dim3(256), 0, stream>>>(K, V, ws);
  if (ws_size >= WS_SPLIT) {
    float* part = (float*)(ws + IMG_TOTAL);
    float* lsw = (float*)(ws + IMG_TOTAL + 2 * PART_BYTES);
    attn_split<<<dim3(512), dim3(256), 0, stream>>>(Q, ws, part, lsw);
    combine<<<dim3(PART_ELEMS / 4 / 256), dim3(256), 0, stream>>>(part, lsw, Out);
  } else {
    attn_fwd15<<<dim3(SEQ / 128 * NB), dim3(256), 0, stream>>>(Q, ws, Out);
  }
}